// Round 14
// baseline (160.704 us; speedup 1.0000x reference)
//
#include <hip/hip_runtime.h>
#include <cstdint>
#include <cstddef>

#define NC 64
#define LN2 0.6931471805599453f

typedef _Float16 half2_t __attribute__((ext_vector_type(2)));
typedef unsigned int uint32x4 __attribute__((ext_vector_type(4)));

static __device__ __forceinline__ float dot2acc(uint32_t a, uint32_t b, float c) {
#if __has_builtin(__builtin_amdgcn_fdot2)
    return __builtin_amdgcn_fdot2(__builtin_bit_cast(half2_t, a),
                                  __builtin_bit_cast(half2_t, b), c, false);
#else
    half2_t ha = __builtin_bit_cast(half2_t, a), hb = __builtin_bit_cast(half2_t, b);
    return c + (float)ha[0] * (float)hb[0] + (float)ha[1] * (float)hb[1];
#endif
}

template <int CTRL>
static __device__ __forceinline__ uint32_t dpp_mov(uint32_t x) {
    return (uint32_t)__builtin_amdgcn_update_dpp(0, (int)x, CTRL, 0xf, 0xf, true);
}
template <int CTRL>
static __device__ __forceinline__ float dppf(float x) {
    return __int_as_float(__builtin_amdgcn_update_dpp(
        0, __float_as_int(x), CTRL, 0xf, 0xf, true));
}
static __device__ __forceinline__ float wave_sum_bcast(float x) {
    x = x + dppf<0x111>(x);
    x = x + dppf<0x112>(x);
    x = x + dppf<0x114>(x);
    x = x + dppf<0x118>(x);
    x = x + dppf<0x142>(x);   // row_bcast15
    x = x + dppf<0x143>(x);   // row_bcast31
    return __int_as_float(__builtin_amdgcn_readlane(__float_as_int(x), 63));
}

// VALU cross-lane swap pairs (semantics probed at runtime -- see E-table fill)
static __device__ __forceinline__ void pl32_pair(uint32_t src, uint32_t& o0, uint32_t& o1) {
    uint32_t a, b;
    asm("v_mov_b32 %0, %2\n\t"
        "v_mov_b32 %1, %2\n\t"
        "v_permlane32_swap_b32 %0, %1"
        : "=&v"(a), "=&v"(b) : "v"(src));
    o0 = a; o1 = b;
}
static __device__ __forceinline__ void pl16_pair(uint32_t src, uint32_t& o0, uint32_t& o1) {
    uint32_t a, b;
    asm("v_mov_b32 %0, %2\n\t"
        "v_mov_b32 %1, %2\n\t"
        "v_permlane16_swap_b32 %0, %1"
        : "=&v"(a), "=&v"(b) : "v"(src));
    o0 = a; o1 = b;
}

// exchange network: value -> 4 words, each {v[x], v[x^1]} at position x=(i&15)|16q
// (register order and lo/hi order are WHATEVER the HW gives; probe absorbs it)
static __device__ __forceinline__ void exchange(uint32_t h, uint32_t& b0, uint32_t& b1,
                                                uint32_t& b2, uint32_t& b3) {
    uint32_t a, b;
    pl32_pair(h, a, b);
    pl16_pair(a, b0, b1);
    pl16_pair(b, b2, b3);
}

// DPP ctrls: 0xB1 ^1, 0x4E ^2, 0x1B ^3, 0x141 ^7 (half_mirror), 0x140 ^15 (mirror)

__global__ __launch_bounds__(128, 1)
void crf_nll_kernel(const float* __restrict__ logits,
                    const float* __restrict__ trans,
                    const float* __restrict__ init_alphas,
                    const int*  __restrict__ lengths,
                    const int*  __restrict__ tags,
                    float* __restrict__ out,
                    int N, int T)
{
    const int n = blockIdx.x;
    const int tid = threadIdx.x;
    const int wid = tid >> 6;          // wave 0: forward alpha; wave 1: backward beta
    const int lane = tid & 63;
    const float* lg = logits + (size_t)n * T * NC;
    const int len = lengths[n];        // in [2, T]
    const int Tm1 = T - 1;

    __shared__ __align__(16) uint32_t Etab[2][64 * 32]; // probed split-dot layout, f16x2
    __shared__ __align__(16) float xchg[2][NC];
    __shared__ float Lsh[2], gsh[2];

    // ---- PROBE the exchange network with lane indices as payload
    uint32_t pb0, pb1, pb2, pb3;
    {
        uint32_t hp = (uint32_t)lane | (((uint32_t)(lane ^ 1)) << 16); // == real pack
        exchange(hp, pb0, pb1, pb2, pb3);
    }

    // ---- fill THIS lane's 32 E-words from probed source indices.
    // word (D_idx, q): partial for row (lane ^ 2*D_idx); classes from probe word q.
    // wave0: exp(trans[row][j]) ; wave1: exp(trans[j][row])  (E^T)
    {
        uint32_t pq[4] = {pb0, pb1, pb2, pb3};
        uint32_t* dst = &Etab[wid][lane * 32];
        #pragma unroll
        for (int d = 0; d < 8; ++d) {
            int row = lane ^ (2 * d);
            #pragma unroll
            for (int q = 0; q < 4; ++q) {
                int j_lo = (int)(pq[q] & 0xFFFFu);
                int j_hi = (int)(pq[q] >> 16);
                float xlo = wid == 0 ? trans[row * NC + j_lo] : trans[j_lo * NC + row];
                float xhi = wid == 0 ? trans[row * NC + j_hi] : trans[j_hi * NC + row];
                uint32_t lo = (uint32_t)__builtin_bit_cast(uint16_t, (_Float16)__expf(xlo));
                uint32_t hi = (uint32_t)__builtin_bit_cast(uint16_t, (_Float16)__expf(xhi));
                dst[d * 4 + q] = lo | (hi << 16);
            }
        }
    }
    __syncthreads();

    // ---- hoist this lane's 128B E block into 8 vec4 regs via inline asm
    // (asm outputs non-rematerializable -> stay resident; proven round 8)
    uint32x4 e0, e1, e2, e3, e4, e5, e6, e7;
    {
        uint32_t e_addr = (uint32_t)(uintptr_t)&Etab[wid][0] + (uint32_t)(lane * 128);
        asm volatile(
            "ds_read_b128 %0, %8 offset:0\n\t"
            "ds_read_b128 %1, %8 offset:16\n\t"
            "ds_read_b128 %2, %8 offset:32\n\t"
            "ds_read_b128 %3, %8 offset:48\n\t"
            "ds_read_b128 %4, %8 offset:64\n\t"
            "ds_read_b128 %5, %8 offset:80\n\t"
            "ds_read_b128 %6, %8 offset:96\n\t"
            "ds_read_b128 %7, %8 offset:112\n\t"
            "s_waitcnt lgkmcnt(0)"
            : "=&v"(e0), "=&v"(e1), "=&v"(e2), "=&v"(e3),
              "=&v"(e4), "=&v"(e5), "=&v"(e6), "=&v"(e7)
            : "v"(e_addr)
            : "memory");
        __builtin_amdgcn_sched_barrier(0);
    }

    const int m  = (len - 1) >> 1;     // forward does m steps
    const int nb = len - 1 - m;        // backward does nb >= 1 steps

    float L = 0.f, vcur = 1.0f, s_cur = 1.0f, dL = 0.0f;

    // all-VALU step: exchange + split-dot + DPP tree. NO DS ops.
    auto dotE = [&](float vv) -> float {
        uint32_t c16 = (uint32_t)__builtin_bit_cast(uint16_t, (_Float16)vv);
        uint32_t h = c16 | (dpp_mov<0xB1>(c16) << 16);   // {v[i], v[i^1]}
        uint32_t b0, b1, b2, b3;
        exchange(h, b0, b1, b2, b3);
        float p0, p1, p2, p3, p4, p5, p6, p7;
        p0 = dot2acc(e0.x, b0, dot2acc(e0.y, b1, dot2acc(e0.z, b2, dot2acc(e0.w, b3, 0.f))));
        p1 = dot2acc(e1.x, b0, dot2acc(e1.y, b1, dot2acc(e1.z, b2, dot2acc(e1.w, b3, 0.f))));
        p2 = dot2acc(e2.x, b0, dot2acc(e2.y, b1, dot2acc(e2.z, b2, dot2acc(e2.w, b3, 0.f))));
        p3 = dot2acc(e3.x, b0, dot2acc(e3.y, b1, dot2acc(e3.z, b2, dot2acc(e3.w, b3, 0.f))));
        p4 = dot2acc(e4.x, b0, dot2acc(e4.y, b1, dot2acc(e4.z, b2, dot2acc(e4.w, b3, 0.f))));
        p5 = dot2acc(e5.x, b0, dot2acc(e5.y, b1, dot2acc(e5.z, b2, dot2acc(e5.w, b3, 0.f))));
        p6 = dot2acc(e6.x, b0, dot2acc(e6.y, b1, dot2acc(e6.z, b2, dot2acc(e6.w, b3, 0.f))));
        p7 = dot2acc(e7.x, b0, dot2acc(e7.y, b1, dot2acc(e7.z, b2, dot2acc(e7.w, b3, 0.f))));
        // butterfly reduce: p_d = partial of row lane^(2d); levels ^2, ^4, ^8
        float q0  = p0 + dppf<0x4E>(p1);                       // ^2
        float q4  = p2 + dppf<0x4E>(p3);
        float q8  = p4 + dppf<0x4E>(p5);
        float q12 = p6 + dppf<0x4E>(p7);
        float r0 = q0 + dppf<0x1B>(dppf<0x141>(q4));           // ^3∘^7 = ^4
        float r8 = q8 + dppf<0x1B>(dppf<0x141>(q12));
        return r0 + dppf<0x140>(dppf<0x141>(r8));              // ^15∘^7 = ^8
    };

    if (wid == 0) {
        // ---------------- forward: alpha_0 .. alpha_m ----------------
        float a0 = init_alphas[lane] + lg[lane];
        L = __int_as_float(__builtin_amdgcn_readfirstlane(__float_as_int(a0))) + 8.f * LN2;
        vcur = __expf(a0 - L);

        auto fstep = [&](float raw) {
            float fs = __expf(raw) * s_cur;
            L += dL;
            float v = fs * dotE(vcur);
            vcur = v;
            unsigned bits = (unsigned)__builtin_amdgcn_readfirstlane((int)__float_as_uint(v));
            int e = (int)((bits >> 23) & 0xFF);
            s_cur = __uint_as_float((unsigned)(246 - e) << 23);   // 2^(119-e)
            dL    = (float)(e - 119) * LN2;
        };

        float r0 = lg[NC * (1 < Tm1 ? 1 : Tm1) + lane];
        float r1 = lg[NC * (2 < Tm1 ? 2 : Tm1) + lane];
        float r2 = lg[NC * (3 < Tm1 ? 3 : Tm1) + lane];
        float r3 = lg[NC * (4 < Tm1 ? 4 : Tm1) + lane];
        float r4 = lg[NC * (5 < Tm1 ? 5 : Tm1) + lane];
        float r5 = lg[NC * (6 < Tm1 ? 6 : Tm1) + lane];
        float r6 = lg[NC * (7 < Tm1 ? 7 : Tm1) + lane];
        float r7 = lg[NC * (8 < Tm1 ? 8 : Tm1) + lane];

        int t = 1;
        for (; t + 8 <= m + 1; t += 8) {
            int p;
            fstep(r0); p = t +  8; p = p < Tm1 ? p : Tm1; r0 = lg[NC * p + lane];
            fstep(r1); p = t +  9; p = p < Tm1 ? p : Tm1; r1 = lg[NC * p + lane];
            fstep(r2); p = t + 10; p = p < Tm1 ? p : Tm1; r2 = lg[NC * p + lane];
            fstep(r3); p = t + 11; p = p < Tm1 ? p : Tm1; r3 = lg[NC * p + lane];
            fstep(r4); p = t + 12; p = p < Tm1 ? p : Tm1; r4 = lg[NC * p + lane];
            fstep(r5); p = t + 13; p = p < Tm1 ? p : Tm1; r5 = lg[NC * p + lane];
            fstep(r6); p = t + 14; p = p < Tm1 ? p : Tm1; r6 = lg[NC * p + lane];
            fstep(r7); p = t + 15; p = p < Tm1 ? p : Tm1; r7 = lg[NC * p + lane];
        }
        if (t + 0 <= m) fstep(r0);
        if (t + 1 <= m) fstep(r1);
        if (t + 2 <= m) fstep(r2);
        if (t + 3 <= m) fstep(r3);
        if (t + 4 <= m) fstep(r4);
        if (t + 5 <= m) fstep(r5);
        if (t + 6 <= m) fstep(r6);
    } else {
        // ---------------- backward: beta_{len-1}=0 down to beta_m ----------------
        auto bstep = [&](float raw) {
            float p = __expf(raw) * s_cur * vcur;   // own-lane product, then E^T gather
            L += dL;
            float u = dotE(p);
            vcur = u;
            unsigned bits = (unsigned)__builtin_amdgcn_readfirstlane((int)__float_as_uint(u));
            int e = (int)((bits >> 23) & 0xFF);
            s_cur = __uint_as_float((unsigned)(246 - e) << 23);   // 2^(119-e)
            dL    = (float)(e - 119) * LN2;
        };

        int p0i;
        p0i = len - 1; p0i = p0i > 1 ? p0i : 1; float r0 = lg[NC * p0i + lane];
        p0i = len - 2; p0i = p0i > 1 ? p0i : 1; float r1 = lg[NC * p0i + lane];
        p0i = len - 3; p0i = p0i > 1 ? p0i : 1; float r2 = lg[NC * p0i + lane];
        p0i = len - 4; p0i = p0i > 1 ? p0i : 1; float r3 = lg[NC * p0i + lane];
        p0i = len - 5; p0i = p0i > 1 ? p0i : 1; float r4 = lg[NC * p0i + lane];
        p0i = len - 6; p0i = p0i > 1 ? p0i : 1; float r5 = lg[NC * p0i + lane];
        p0i = len - 7; p0i = p0i > 1 ? p0i : 1; float r6 = lg[NC * p0i + lane];
        p0i = len - 8; p0i = p0i > 1 ? p0i : 1; float r7 = lg[NC * p0i + lane];

        int k = 0;
        for (; k + 8 <= nb; k += 8) {
            int p;
            bstep(r0); p = len - 1 - (k +  8); p = p > 1 ? p : 1; r0 = lg[NC * p + lane];
            bstep(r1); p = len - 1 - (k +  9); p = p > 1 ? p : 1; r1 = lg[NC * p + lane];
            bstep(r2); p = len - 1 - (k + 10); p = p > 1 ? p : 1; r2 = lg[NC * p + lane];
            bstep(r3); p = len - 1 - (k + 11); p = p > 1 ? p : 1; r3 = lg[NC * p + lane];
            bstep(r4); p = len - 1 - (k + 12); p = p > 1 ? p : 1; r4 = lg[NC * p + lane];
            bstep(r5); p = len - 1 - (k + 13); p = p > 1 ? p : 1; r5 = lg[NC * p + lane];
            bstep(r6); p = len - 1 - (k + 14); p = p > 1 ? p : 1; r6 = lg[NC * p + lane];
            bstep(r7); p = len - 1 - (k + 15); p = p > 1 ? p : 1; r7 = lg[NC * p + lane];
        }
        if (k + 0 < nb) bstep(r0);
        if (k + 1 < nb) bstep(r1);
        if (k + 2 < nb) bstep(r2);
        if (k + 3 < nb) bstep(r3);
        if (k + 4 < nb) bstep(r4);
        if (k + 5 < nb) bstep(r5);
        if (k + 6 < nb) bstep(r6);
    }

    // ---- publish per-wave results
    xchg[wid][lane] = vcur;
    if (lane == 0) Lsh[wid] = L;

    // ---- gold score: both waves cooperate (128-thread stride)
    const int* tg = tags + (size_t)n * T;
    float g = 0.f;
    for (int tt = 1 + tid; tt < len; tt += 128) {
        const int cur = tg[tt];
        const int prv = tg[tt - 1];
        g += trans[cur * NC + prv] + lg[tt * NC + cur];
    }
    g = wave_sum_bcast(g);
    if (lane == 0) gsh[wid] = g;

    __syncthreads();

    if (wid == 0) {
        float prod = xchg[0][lane] * xchg[1][lane];
        float ssum = wave_sum_bcast(prod);
        if (lane == 0) {
            float logZ = Lsh[0] + Lsh[1] + __logf(ssum);
            int t0v = tg[0];
            float gold = init_alphas[t0v] + lg[t0v] + gsh[0] + gsh[1];
            out[n] = logZ - gold;
        }
    }
}

extern "C" void kernel_launch(void* const* d_in, const int* in_sizes, int n_in,
                              void* d_out, int out_size, void* d_ws, size_t ws_size,
                              hipStream_t stream)
{
    const float* logits = (const float*)d_in[0];   // [N][T][C] f32
    const float* trans  = (const float*)d_in[1];   // [C][C]    f32
    const float* inita  = (const float*)d_in[2];   // [C]       f32
    const int*   lens   = (const int*)d_in[3];     // [N]       i32
    const int*   tags   = (const int*)d_in[4];     // [N][T]    i32
    float*       out    = (float*)d_out;           // [N]       f32

    const int N = 512, T = 1024;
    crf_nll_kernel<<<N, 128, 0, stream>>>(logits, trans, inita, lens, tags, out, N, T);
}

// Round 15
// 145.317 us; speedup vs baseline: 1.1059x; 1.1059x over previous
//
#include <hip/hip_runtime.h>
#include <cstdint>
#include <cstddef>

#define NC 64
#define LN2 0.6931471805599453f

typedef _Float16 half2_t __attribute__((ext_vector_type(2)));
typedef unsigned int uint32x4 __attribute__((ext_vector_type(4)));

static __device__ __forceinline__ float dot2acc(uint32_t a, uint32_t b, float c) {
#if __has_builtin(__builtin_amdgcn_fdot2)
    return __builtin_amdgcn_fdot2(__builtin_bit_cast(half2_t, a),
                                  __builtin_bit_cast(half2_t, b), c, false);
#else
    half2_t ha = __builtin_bit_cast(half2_t, a), hb = __builtin_bit_cast(half2_t, b);
    return c + (float)ha[0] * (float)hb[0] + (float)ha[1] * (float)hb[1];
#endif
}

template <int CTRL>
static __device__ __forceinline__ uint32_t dpp_mov(uint32_t x) {
    return (uint32_t)__builtin_amdgcn_update_dpp(0, (int)x, CTRL, 0xf, 0xf, true);
}
template <int CTRL>
static __device__ __forceinline__ float dppf(float x) {
    return __int_as_float(__builtin_amdgcn_update_dpp(
        0, __float_as_int(x), CTRL, 0xf, 0xf, true));
}
static __device__ __forceinline__ float wave_sum_bcast(float x) {
    x = x + dppf<0x111>(x);
    x = x + dppf<0x112>(x);
    x = x + dppf<0x114>(x);
    x = x + dppf<0x118>(x);
    x = x + dppf<0x142>(x);   // row_bcast15
    x = x + dppf<0x143>(x);   // row_bcast31
    return __int_as_float(__builtin_amdgcn_readlane(__float_as_int(x), 63));
}

// DPP ctrls: 0xB1 ^1, 0x4E ^2, 0x1B ^3, 0x141 ^7 (half_mirror), 0x140 ^15 (mirror)
// Transport primitives (ALL verified exact in round 9: absmax 0.0, zero added conflicts):
//   ds_swizzle 0x401F  : lane i <- lane i^16
//   ds_bpermute addr=(i^32)<<2 : lane i <- lane i^32   (bijective, conflict-free)
//   ds_bpermute addr=(i^48)<<2 : lane i <- lane i^48

__global__ __launch_bounds__(128, 1)
void crf_nll_kernel(const float* __restrict__ logits,
                    const float* __restrict__ trans,
                    const float* __restrict__ init_alphas,
                    const int*  __restrict__ lengths,
                    const int*  __restrict__ tags,
                    float* __restrict__ out,
                    int N, int T)
{
    const int n = blockIdx.x;
    const int tid = threadIdx.x;
    const int wid = tid >> 6;          // wave 0: forward alpha; wave 1: backward beta
    const int lane = tid & 63;
    const float* lg = logits + (size_t)n * T * NC;
    const int len = lengths[n];        // in [2, T]
    const int Tm1 = T - 1;

    __shared__ __align__(16) uint32_t Etab[2][64 * 32]; // probed split-dot E layout, f16x2
    __shared__ __align__(16) float xchg[2][NC];
    __shared__ float Lsh[2], gsh[2];

    const int ba32 = (lane ^ 32) << 2;   // bpermute byte addr for ^32
    const int ba48 = (lane ^ 48) << 2;   // bpermute byte addr for ^48

    // ---- PROBE the transport with lane indices as payload (absorbs all semantics)
    uint32_t pq0, pq1, pq2, pq3;
    {
        uint32_t hp = (uint32_t)lane | (((uint32_t)(lane ^ 1)) << 16); // == real pack
        pq0 = hp;                                                      // word 0: own
        pq1 = (uint32_t)__builtin_amdgcn_ds_swizzle((int)hp, 0x401F);  // ^16
        pq2 = (uint32_t)__builtin_amdgcn_ds_bpermute(ba32, (int)hp);   // ^32
        pq3 = (uint32_t)__builtin_amdgcn_ds_bpermute(ba48, (int)hp);   // ^48
    }

    // ---- fill THIS lane's 32 E-words from probed source indices.
    // word (d, q): partial for row (lane ^ 2d); classes {j_lo, j_hi} from probe word q.
    // wave0: exp(trans[row][j]) ; wave1: exp(trans[j][row])  (E^T)
    {
        uint32_t pq[4] = {pq0, pq1, pq2, pq3};
        uint32_t* dst = &Etab[wid][lane * 32];
        #pragma unroll
        for (int d = 0; d < 8; ++d) {
            int row = lane ^ (2 * d);
            #pragma unroll
            for (int q = 0; q < 4; ++q) {
                int j_lo = (int)(pq[q] & 0xFFFFu);
                int j_hi = (int)(pq[q] >> 16);
                float xlo = wid == 0 ? trans[row * NC + j_lo] : trans[j_lo * NC + row];
                float xhi = wid == 0 ? trans[row * NC + j_hi] : trans[j_hi * NC + row];
                uint32_t lo = (uint32_t)__builtin_bit_cast(uint16_t, (_Float16)__expf(xlo));
                uint32_t hi = (uint32_t)__builtin_bit_cast(uint16_t, (_Float16)__expf(xhi));
                dst[d * 4 + q] = lo | (hi << 16);
            }
        }
    }
    __syncthreads();

    // ---- hoist this lane's 128B E block into 8 vec4 regs via inline asm
    // (asm outputs non-rematerializable -> stay resident; proven round 8)
    uint32x4 e0, e1, e2, e3, e4, e5, e6, e7;
    {
        uint32_t e_addr = (uint32_t)(uintptr_t)&Etab[wid][0] + (uint32_t)(lane * 128);
        asm volatile(
            "ds_read_b128 %0, %8 offset:0\n\t"
            "ds_read_b128 %1, %8 offset:16\n\t"
            "ds_read_b128 %2, %8 offset:32\n\t"
            "ds_read_b128 %3, %8 offset:48\n\t"
            "ds_read_b128 %4, %8 offset:64\n\t"
            "ds_read_b128 %5, %8 offset:80\n\t"
            "ds_read_b128 %6, %8 offset:96\n\t"
            "ds_read_b128 %7, %8 offset:112\n\t"
            "s_waitcnt lgkmcnt(0)"
            : "=&v"(e0), "=&v"(e1), "=&v"(e2), "=&v"(e3),
              "=&v"(e4), "=&v"(e5), "=&v"(e6), "=&v"(e7)
            : "v"(e_addr)
            : "memory");
        __builtin_amdgcn_sched_barrier(0);
    }

    const int m  = (len - 1) >> 1;     // forward does m steps
    const int nb = len - 1 - m;        // backward does nb >= 1 steps

    float L = 0.f, vcur = 1.0f, s_cur = 1.0f, dL = 0.0f;

    // step core: pack pairs, 3 independent crossbar ops, split-dot, DPP tree.
    // h-dots (word 0) issue during the DS-crossbar latency.
    auto dotE = [&](float vv) -> float {
        uint32_t c16 = (uint32_t)__builtin_bit_cast(uint16_t, (_Float16)vv);
        uint32_t h = c16 | (dpp_mov<0xB1>(c16) << 16);   // {v[i], v[i^1]}
        uint32_t w1 = (uint32_t)__builtin_amdgcn_ds_swizzle((int)h, 0x401F);  // ^16
        uint32_t w2 = (uint32_t)__builtin_amdgcn_ds_bpermute(ba32, (int)h);   // ^32
        uint32_t w3 = (uint32_t)__builtin_amdgcn_ds_bpermute(ba48, (int)h);   // ^48
        float p0, p1, p2, p3, p4, p5, p6, p7;
        // innermost (h) evaluates first -> overlaps the crossbar latency
        p0 = dot2acc(e0.w, w3, dot2acc(e0.z, w2, dot2acc(e0.y, w1, dot2acc(e0.x, h, 0.f))));
        p1 = dot2acc(e1.w, w3, dot2acc(e1.z, w2, dot2acc(e1.y, w1, dot2acc(e1.x, h, 0.f))));
        p2 = dot2acc(e2.w, w3, dot2acc(e2.z, w2, dot2acc(e2.y, w1, dot2acc(e2.x, h, 0.f))));
        p3 = dot2acc(e3.w, w3, dot2acc(e3.z, w2, dot2acc(e3.y, w1, dot2acc(e3.x, h, 0.f))));
        p4 = dot2acc(e4.w, w3, dot2acc(e4.z, w2, dot2acc(e4.y, w1, dot2acc(e4.x, h, 0.f))));
        p5 = dot2acc(e5.w, w3, dot2acc(e5.z, w2, dot2acc(e5.y, w1, dot2acc(e5.x, h, 0.f))));
        p6 = dot2acc(e6.w, w3, dot2acc(e6.z, w2, dot2acc(e6.y, w1, dot2acc(e6.x, h, 0.f))));
        p7 = dot2acc(e7.w, w3, dot2acc(e7.z, w2, dot2acc(e7.y, w1, dot2acc(e7.x, h, 0.f))));
        // symbolically-verified reduce tree: p_d = partial of row lane^(2d)
        float q0  = p0 + dppf<0x4E>(p1);                       // ^2
        float q4  = p2 + dppf<0x4E>(p3);
        float q8  = p4 + dppf<0x4E>(p5);
        float q12 = p6 + dppf<0x4E>(p7);
        float r0 = q0 + dppf<0x1B>(dppf<0x141>(q4));           // ^3∘^7 = ^4
        float r8 = q8 + dppf<0x1B>(dppf<0x141>(q12));
        return r0 + dppf<0x140>(dppf<0x141>(r8));              // ^15∘^7 = ^8
    };

    if (wid == 0) {
        // ---------------- forward: alpha_0 .. alpha_m ----------------
        float a0 = init_alphas[lane] + lg[lane];
        L = __int_as_float(__builtin_amdgcn_readfirstlane(__float_as_int(a0))) + 8.f * LN2;
        vcur = __expf(a0 - L);

        auto fstep = [&](float raw) {
            float fs = __expf(raw) * s_cur;
            L += dL;
            float v = fs * dotE(vcur);
            vcur = v;
            unsigned bits = (unsigned)__builtin_amdgcn_readfirstlane((int)__float_as_uint(v));
            int e = (int)((bits >> 23) & 0xFF);
            s_cur = __uint_as_float((unsigned)(246 - e) << 23);   // 2^(119-e)
            dL    = (float)(e - 119) * LN2;
        };

        float r0 = lg[NC * (1 < Tm1 ? 1 : Tm1) + lane];
        float r1 = lg[NC * (2 < Tm1 ? 2 : Tm1) + lane];
        float r2 = lg[NC * (3 < Tm1 ? 3 : Tm1) + lane];
        float r3 = lg[NC * (4 < Tm1 ? 4 : Tm1) + lane];
        float r4 = lg[NC * (5 < Tm1 ? 5 : Tm1) + lane];
        float r5 = lg[NC * (6 < Tm1 ? 6 : Tm1) + lane];
        float r6 = lg[NC * (7 < Tm1 ? 7 : Tm1) + lane];
        float r7 = lg[NC * (8 < Tm1 ? 8 : Tm1) + lane];

        int t = 1;
        for (; t + 8 <= m + 1; t += 8) {
            int p;
            fstep(r0); p = t +  8; p = p < Tm1 ? p : Tm1; r0 = lg[NC * p + lane];
            fstep(r1); p = t +  9; p = p < Tm1 ? p : Tm1; r1 = lg[NC * p + lane];
            fstep(r2); p = t + 10; p = p < Tm1 ? p : Tm1; r2 = lg[NC * p + lane];
            fstep(r3); p = t + 11; p = p < Tm1 ? p : Tm1; r3 = lg[NC * p + lane];
            fstep(r4); p = t + 12; p = p < Tm1 ? p : Tm1; r4 = lg[NC * p + lane];
            fstep(r5); p = t + 13; p = p < Tm1 ? p : Tm1; r5 = lg[NC * p + lane];
            fstep(r6); p = t + 14; p = p < Tm1 ? p : Tm1; r6 = lg[NC * p + lane];
            fstep(r7); p = t + 15; p = p < Tm1 ? p : Tm1; r7 = lg[NC * p + lane];
        }
        if (t + 0 <= m) fstep(r0);
        if (t + 1 <= m) fstep(r1);
        if (t + 2 <= m) fstep(r2);
        if (t + 3 <= m) fstep(r3);
        if (t + 4 <= m) fstep(r4);
        if (t + 5 <= m) fstep(r5);
        if (t + 6 <= m) fstep(r6);
    } else {
        // ---------------- backward: beta_{len-1}=0 down to beta_m ----------------
        auto bstep = [&](float raw) {
            float p = __expf(raw) * s_cur * vcur;   // own-lane product, then E^T gather
            L += dL;
            float u = dotE(p);
            vcur = u;
            unsigned bits = (unsigned)__builtin_amdgcn_readfirstlane((int)__float_as_uint(u));
            int e = (int)((bits >> 23) & 0xFF);
            s_cur = __uint_as_float((unsigned)(246 - e) << 23);   // 2^(119-e)
            dL    = (float)(e - 119) * LN2;
        };

        int p0i;
        p0i = len - 1; p0i = p0i > 1 ? p0i : 1; float r0 = lg[NC * p0i + lane];
        p0i = len - 2; p0i = p0i > 1 ? p0i : 1; float r1 = lg[NC * p0i + lane];
        p0i = len - 3; p0i = p0i > 1 ? p0i : 1; float r2 = lg[NC * p0i + lane];
        p0i = len - 4; p0i = p0i > 1 ? p0i : 1; float r3 = lg[NC * p0i + lane];
        p0i = len - 5; p0i = p0i > 1 ? p0i : 1; float r4 = lg[NC * p0i + lane];
        p0i = len - 6; p0i = p0i > 1 ? p0i : 1; float r5 = lg[NC * p0i + lane];
        p0i = len - 7; p0i = p0i > 1 ? p0i : 1; float r6 = lg[NC * p0i + lane];
        p0i = len - 8; p0i = p0i > 1 ? p0i : 1; float r7 = lg[NC * p0i + lane];

        int k = 0;
        for (; k + 8 <= nb; k += 8) {
            int p;
            bstep(r0); p = len - 1 - (k +  8); p = p > 1 ? p : 1; r0 = lg[NC * p + lane];
            bstep(r1); p = len - 1 - (k +  9); p = p > 1 ? p : 1; r1 = lg[NC * p + lane];
            bstep(r2); p = len - 1 - (k + 10); p = p > 1 ? p : 1; r2 = lg[NC * p + lane];
            bstep(r3); p = len - 1 - (k + 11); p = p > 1 ? p : 1; r3 = lg[NC * p + lane];
            bstep(r4); p = len - 1 - (k + 12); p = p > 1 ? p : 1; r4 = lg[NC * p + lane];
            bstep(r5); p = len - 1 - (k + 13); p = p > 1 ? p : 1; r5 = lg[NC * p + lane];
            bstep(r6); p = len - 1 - (k + 14); p = p > 1 ? p : 1; r6 = lg[NC * p + lane];
            bstep(r7); p = len - 1 - (k + 15); p = p > 1 ? p : 1; r7 = lg[NC * p + lane];
        }
        if (k + 0 < nb) bstep(r0);
        if (k + 1 < nb) bstep(r1);
        if (k + 2 < nb) bstep(r2);
        if (k + 3 < nb) bstep(r3);
        if (k + 4 < nb) bstep(r4);
        if (k + 5 < nb) bstep(r5);
        if (k + 6 < nb) bstep(r6);
    }

    // ---- publish per-wave results
    xchg[wid][lane] = vcur;
    if (lane == 0) Lsh[wid] = L;

    // ---- gold score: both waves cooperate (128-thread stride)
    const int* tg = tags + (size_t)n * T;
    float g = 0.f;
    for (int tt = 1 + tid; tt < len; tt += 128) {
        const int cur = tg[tt];
        const int prv = tg[tt - 1];
        g += trans[cur * NC + prv] + lg[tt * NC + cur];
    }
    g = wave_sum_bcast(g);
    if (lane == 0) gsh[wid] = g;

    __syncthreads();

    if (wid == 0) {
        float prod = xchg[0][lane] * xchg[1][lane];
        float ssum = wave_sum_bcast(prod);
        if (lane == 0) {
            float logZ = Lsh[0] + Lsh[1] + __logf(ssum);
            int t0v = tg[0];
            float gold = init_alphas[t0v] + lg[t0v] + gsh[0] + gsh[1];
            out[n] = logZ - gold;
        }
    }
}

extern "C" void kernel_launch(void* const* d_in, const int* in_sizes, int n_in,
                              void* d_out, int out_size, void* d_ws, size_t ws_size,
                              hipStream_t stream)
{
    const float* logits = (const float*)d_in[0];   // [N][T][C] f32
    const float* trans  = (const float*)d_in[1];   // [C][C]    f32
    const float* inita  = (const float*)d_in[2];   // [C]       f32
    const int*   lens   = (const int*)d_in[3];     // [N]       i32
    const int*   tags   = (const int*)d_in[4];     // [N][T]    i32
    float*       out    = (float*)d_out;           // [N]       f32

    const int N = 512, T = 1024;
    crf_nll_kernel<<<N, 128, 0, stream>>>(logits, trans, inita, lens, tags, out, N, T);
}